// Round 6
// baseline (648.532 us; speedup 1.0000x reference)
//
#include <hip/hip_runtime.h>

#define HW 3136
#define NB 8
#define CD 128
// C^-0.5 * log2(e), folded into the Q projection so attn uses exp2 directly
#define QSCALE 0.12751750206f

typedef __attribute__((ext_vector_type(8))) short short8;
typedef __attribute__((ext_vector_type(4))) float floatx4;
typedef __attribute__((ext_vector_type(4))) unsigned short ushort4v;

static __device__ __forceinline__ unsigned short f2b(float f){
  union { float f; unsigned u; } v; v.f = f;
  unsigned r = v.u + 0x7FFFu + ((v.u >> 16) & 1u);
  return (unsigned short)(r >> 16);
}
static __device__ __forceinline__ unsigned short f2b_trunc(float f){
  union { float f; unsigned u; } v; v.f = f;
  return (unsigned short)(v.u >> 16);
}
static __device__ __forceinline__ float b2f(unsigned short h){
  union { unsigned u; float f; } v; v.u = ((unsigned)h) << 16;
  return v.f;
}

// ---------------------------------------------------------------------------
// 1x1 conv projections via MFMA. W fragments held in REGISTERS per wave
// (wave w owns output channels [32w,32w+32)); X^T staged in LDS per batch.
// grid (49 hw-tiles, 4 batch-pairs, 5 jobs) = 980 blocks.
// ---------------------------------------------------------------------------
__global__ __launch_bounds__(256) void proj_kernel(
    const float* __restrict__ s, const float* __restrict__ t1, const float* __restrict__ t2,
    const float* __restrict__ wq, const float* __restrict__ bq,
    const float* __restrict__ wk, const float* __restrict__ bk,
    const float* __restrict__ wv, const float* __restrict__ bv,
    unsigned short* __restrict__ qkv)
{
  __shared__ __align__(16) unsigned short XT[64][132];   // 16.9 KB
  const int job = blockIdx.z;
  const float* x; const float* w; const float* bias; float scl; int cmajor; size_t dstoff;
  switch(job){
    case 0: x=s;  w=wq; bias=bq; scl=QSCALE; cmajor=0; dstoff=0; break;
    case 1: x=t1; w=wk; bias=bk; scl=1.f;    cmajor=0; dstoff=1; break;
    case 2: x=t1; w=wv; bias=bv; scl=1.f;    cmajor=1; dstoff=2; break;
    case 3: x=t2; w=wk; bias=bk; scl=1.f;    cmajor=0; dstoff=3; break;
    default:x=t2; w=wv; bias=bv; scl=1.f;    cmajor=1; dstoff=4; break;
  }
  const size_t TS = (size_t)NB*HW*CD;
  const int hw0 = blockIdx.x * 64;
  const int tid = threadIdx.x;
  const int m = tid & 15, quad = (tid >> 4) & 3, wv_ = tid >> 6;

  // W fragments in registers: wave wv_ -> nt = 2*wv_ + i (o in [32wv_,32wv_+32))
  short8 wf[2][4];
  float  bb[2];
  for (int i=0;i<2;i++){
    int o = (2*wv_ + i)*16 + m;
    bb[i] = bias[o];
    for (int dk=0;dk<4;dk++){
      const float* wp = w + (size_t)o*CD + dk*32 + quad*8;
      floatx4 w0 = *(const floatx4*)wp;
      floatx4 w1 = *(const floatx4*)(wp+4);
      short8 f;
      for (int j=0;j<4;j++){ f[j] = (short)f2b(w0[j]); f[4+j] = (short)f2b(w1[j]); }
      wf[i][dk] = f;
    }
  }

  for (int bb2 = 0; bb2 < 2; bb2++){
    const int b = blockIdx.y*2 + bb2;
    __syncthreads();                       // prev-iter XT readers done
    const float* xb = x + (size_t)b*CD*HW + hw0;
    for (int it = 0; it < 8; it++){
      int flat = (tid + it*256)*4;         // c*64 + hh
      int c = flat >> 6, hh = flat & 63;
      floatx4 xv = *(const floatx4*)(xb + (size_t)c*HW + hh);
      for (int j=0;j<4;j++) XT[hh+j][c] = f2b(xv[j]);
    }
    __syncthreads();

    short8 af[4][4];
    for (int mt=0;mt<4;mt++)
      for (int dk=0;dk<4;dk++)
        af[mt][dk] = *(const short8*)&XT[mt*16 + m][dk*32 + quad*8];

    floatx4 acc[4][2];
    for (int mt=0;mt<4;mt++)
      for (int i=0;i<2;i++)
        acc[mt][i] = (floatx4){bb[i],bb[i],bb[i],bb[i]};
    for (int mt=0;mt<4;mt++)
      for (int i=0;i<2;i++)
        for (int dk=0;dk<4;dk++)
          acc[mt][i] = __builtin_amdgcn_mfma_f32_16x16x32_bf16(af[mt][dk], wf[i][dk], acc[mt][i], 0,0,0);

    if (!cmajor){
      unsigned short* dstK = qkv + dstoff*TS + ((size_t)b*HW + hw0)*CD;
      for (int mt=0;mt<4;mt++)
        for (int i=0;i<2;i++)
          for (int r=0;r<4;r++)
            dstK[(size_t)(mt*16 + quad*4 + r)*CD + (2*wv_+i)*16 + m] = f2b(acc[mt][i][r]*scl);
    } else {
      unsigned short* dstV = qkv + dstoff*TS + (size_t)b*CD*HW;
      for (int mt=0;mt<4;mt++)
        for (int i=0;i<2;i++){
          ushort4v pk;
          for (int r=0;r<4;r++) pk[r] = f2b(acc[mt][i][r]*scl);
          *(ushort4v*)&dstV[(size_t)((2*wv_+i)*16 + m)*HW + hw0 + mt*16 + quad*4] = pk;
        }
    }
  }
}

// ---------------------------------------------------------------------------
// Flash attention with K-SPLIT (max-free softmax => partials are additive).
// grid 800 = 25 qt x 16 (b,t) x 2 ksplit -> ~12 waves/CU residency (the R2
// level) while keeping dual m-tiles/wave (2x LDS reuse) and conflict-free
// strides. Writes unnormalized bf16 O-partials + f32 l-partials.
// ---------------------------------------------------------------------------
#define KSTR 132
#define VSTR 68
#define PSTR 68
#define KL_E (64*KSTR)
#define VL_E (128*VSTR)
#define PL_E (4*32*PSTR)

__global__ __launch_bounds__(256,3) void attn_kernel(
    const unsigned short* __restrict__ qkv,
    unsigned short* __restrict__ Og,
    float* __restrict__ Lp)
{
  __shared__ __align__(16) unsigned short smem[KL_E + VL_E + PL_E]; // 51712 B
  unsigned short (*Kl)[KSTR] = (unsigned short(*)[KSTR])smem;
  unsigned short (*Vl)[VSTR] = (unsigned short(*)[VSTR])(smem + KL_E);
  unsigned short (*Pl)[PSTR] = (unsigned short(*)[PSTR])(smem + KL_E + VL_E);

  // lin = (qt*2 + ks)*16 + g : all 50 blocks of one (b,t) share lin mod 16
  const int lin = blockIdx.x;
  const int g   = lin & 15;
  const int qk  = lin >> 4;
  const int qt  = qk >> 1;          // 0..24
  const int ks  = qk & 1;           // key split
  const int b   = g >> 1;
  const int t   = g & 1;
  const int kt0 = ks ? 25 : 0;      // keys [0,1600) / [1600,3136)
  const int ktN = ks ? 49 : 25;

  const size_t TS = (size_t)NB*HW*CD;
  const unsigned short* Q = qkv + (size_t)b*HW*CD;
  const unsigned short* K = qkv + TS*(size_t)(1 + 2*t) + (size_t)b*HW*CD;
  const unsigned short* V = qkv + TS*(size_t)(2 + 2*t) + (size_t)b*CD*HW;

  const int tid  = threadIdx.x;
  const int w    = tid >> 6;
  const int lane = tid & 63;
  const int m    = lane & 15;
  const int quad = lane >> 4;
  const int q0w  = qt*128 + w*32;   // wave's 32 q rows (2 m-tiles)

  short8 qf[2][4];
  for (int mt=0;mt<2;mt++){
    int qrow = q0w + mt*16 + m; if (qrow >= HW) qrow = HW-1;
    const unsigned short* qr = Q + (size_t)qrow*CD + quad*8;
    for (int dk=0;dk<4;dk++) qf[mt][dk] = *(const short8*)(qr + dk*32);
  }
  floatx4 Oc[2][8];
  for (int mt=0;mt<2;mt++) for (int i=0;i<8;i++) Oc[mt][i] = (floatx4)0.f;
  float lr[2][4] = {{0.f,0.f,0.f,0.f},{0.f,0.f,0.f,0.f}};

  const unsigned short* kg = K + (size_t)kt0*64*CD + (size_t)(tid>>4)*CD + (tid&15)*8;
  const unsigned short* vg = V + (size_t)(tid>>3)*HW + kt0*64 + (tid&7)*8;
  unsigned short* klds = &Kl[tid>>4][(tid&15)*8];
  unsigned short* vlds = &Vl[tid>>3][(tid&7)*8];

  short8 kpre[4], vpre[4];
  for (int i=0;i<4;i++) kpre[i] = *(const short8*)(kg + (size_t)i*16*CD);
  for (int i=0;i<4;i++) vpre[i] = *(const short8*)(vg + (size_t)i*32*HW);

  for (int kt = kt0; kt < ktN; kt++){
    __syncthreads();
    for (int i=0;i<4;i++) *(short8*)(klds + i*16*KSTR) = kpre[i];
    for (int i=0;i<4;i++) *(short8*)(vlds + i*32*VSTR) = vpre[i];
    __syncthreads();
    if (kt < ktN - 1){
      kg += 64*CD; vg += 64;
      for (int i=0;i<4;i++) kpre[i] = *(const short8*)(kg + (size_t)i*16*CD);
      for (int i=0;i<4;i++) vpre[i] = *(const short8*)(vg + (size_t)i*32*HW);
    }

    // scores per nt-tile: each kf read feeds both m-tiles
    for (int nt=0;nt<4;nt++){
      floatx4 s0 = (floatx4)0.f, s1 = (floatx4)0.f;
      for (int dk=0;dk<4;dk++){
        short8 kf = *(const short8*)&Kl[nt*16 + m][dk*32 + quad*8];
        s0 = __builtin_amdgcn_mfma_f32_16x16x32_bf16(qf[0][dk], kf, s0, 0,0,0);
        s1 = __builtin_amdgcn_mfma_f32_16x16x32_bf16(qf[1][dk], kf, s1, 0,0,0);
      }
      for (int r=0;r<4;r++){
        float p0 = __builtin_amdgcn_exp2f(s0[r]);
        float p1 = __builtin_amdgcn_exp2f(s1[r]);
        lr[0][r] += p0;
        lr[1][r] += p1;
        Pl[w*32      + quad*4 + r][nt*16 + m] = f2b_trunc(p0);
        Pl[w*32 + 16 + quad*4 + r][nt*16 + m] = f2b_trunc(p1);
      }
    }
    __asm__ volatile("s_waitcnt lgkmcnt(0)" ::: "memory");  // same-wave P rows
    short8 pf[2][2];
    for (int mt=0;mt<2;mt++)
      for (int kk=0;kk<2;kk++)
        pf[mt][kk] = *(const short8*)&Pl[w*32 + mt*16 + m][kk*32 + quad*8];
    for (int ct=0;ct<8;ct++){
      short8 vf0 = *(const short8*)&Vl[ct*16 + m][quad*8];
      short8 vf1 = *(const short8*)&Vl[ct*16 + m][32 + quad*8];
      Oc[0][ct] = __builtin_amdgcn_mfma_f32_16x16x32_bf16(pf[0][0], vf0, Oc[0][ct], 0,0,0);
      Oc[0][ct] = __builtin_amdgcn_mfma_f32_16x16x32_bf16(pf[0][1], vf1, Oc[0][ct], 0,0,0);
      Oc[1][ct] = __builtin_amdgcn_mfma_f32_16x16x32_bf16(pf[1][0], vf0, Oc[1][ct], 0,0,0);
      Oc[1][ct] = __builtin_amdgcn_mfma_f32_16x16x32_bf16(pf[1][1], vf1, Oc[1][ct], 0,0,0);
    }
  }

  // l partial: reduce across the 16 column-lanes of each quad (no normalize)
  for (int mt=0;mt<2;mt++)
    for (int r=0;r<4;r++)
      for (int off=1; off<16; off<<=1)
        lr[mt][r] += __shfl_xor(lr[mt][r], off, 64);

  __syncthreads();                          // done with K/V/P LDS; reuse as staging
  unsigned short* stg = smem + w*(32*KSTR); // 32x132 bf16 per wave
  for (int mt=0;mt<2;mt++)
    for (int ct=0;ct<8;ct++)
      for (int r=0;r<4;r++)
        stg[(mt*16 + quad*4 + r)*KSTR + ct*16 + m] = f2b(Oc[mt][ct][r]);
  __asm__ volatile("s_waitcnt lgkmcnt(0)" ::: "memory");    // per-wave region
  if (q0w < HW){
    const size_t strm = (size_t)(ks*2 + t)*NB + b;
    unsigned short* ob = Og + strm*HW*CD + (size_t)q0w*CD;
    for (int i=0;i<8;i++){
      int row = i*4 + quad;
      short8 v8 = *(const short8*)&stg[row*KSTR + m*8];
      *(short8*)&ob[(size_t)row*CD + m*8] = v8;
    }
    if (m == 0){
      float* lb = Lp + strm*HW + q0w;
      for (int mt=0;mt<2;mt++)
        for (int r=0;r<4;r++)
          lb[mt*16 + quad*4 + r] = lr[mt][r];
    }
  }
}

// ---------------------------------------------------------------------------
// out[b,c,hw] = s + 0.5 * sum_t (O_t0+O_t1)/(l_t0+l_t1)   (partial combine)
// ---------------------------------------------------------------------------
__global__ __launch_bounds__(256) void combine_kernel(
    const float* __restrict__ s, const unsigned short* __restrict__ Og,
    const float* __restrict__ Lp, float* __restrict__ out)
{
  __shared__ float T[32][129];
  const int b   = blockIdx.y;
  const int hw0 = blockIdx.x * 32;
  const int tid = threadIdx.x;
  const size_t OS = (size_t)NB*HW*CD;      // per-(ks,t) O stride
  const size_t LS = (size_t)NB*HW;         // per-(ks,t) l stride
  const unsigned short* Ob = Og + ((size_t)b*HW + hw0)*CD;
  const float* Lb = Lp + (size_t)b*HW + hw0;

  for (int i=0;i<2;i++){
    int flat = (tid + i*256)*8;
    int row = flat >> 7, col = flat & 127;
    size_t off = (size_t)row*CD + col;
    short8 o00 = *(const short8*)(Ob + off);          // ks0,t0
    short8 o01 = *(const short8*)(Ob + OS   + off);   // ks0,t1
    short8 o10 = *(const short8*)(Ob + 2*OS + off);   // ks1,t0
    short8 o11 = *(const short8*)(Ob + 3*OS + off);   // ks1,t1
    float inv0 = 1.f / (Lb[row] + Lb[2*LS + row]);
    float inv1 = 1.f / (Lb[LS + row] + Lb[3*LS + row]);
    for (int j=0;j<8;j++)
      T[row][col+j] = 0.5f*((b2f((unsigned short)o00[j]) + b2f((unsigned short)o10[j]))*inv0
                          + (b2f((unsigned short)o01[j]) + b2f((unsigned short)o11[j]))*inv1);
  }
  __syncthreads();
  const int c  = tid >> 1;
  const int h0 = (tid & 1)*16;
  const float* sr = s   + ((size_t)b*CD + c)*HW + hw0 + h0;
  float*     orow = out + ((size_t)b*CD + c)*HW + hw0 + h0;
  for (int j0=0;j0<16;j0+=4){
    floatx4 sv = *(const floatx4*)(sr + j0);
    floatx4 ov;
    for (int jj=0;jj<4;jj++) ov[jj] = sv[jj] + T[h0+j0+jj][c];
    *(floatx4*)(orow + j0) = ov;
  }
}

extern "C" void kernel_launch(void* const* d_in, const int* in_sizes, int n_in,
                              void* d_out, int out_size, void* d_ws, size_t ws_size,
                              hipStream_t stream)
{
  const float* s  = (const float*)d_in[0];
  const float* t1 = (const float*)d_in[1];
  const float* t2 = (const float*)d_in[2];
  const float* wq = (const float*)d_in[3];
  const float* bq = (const float*)d_in[4];
  const float* wk = (const float*)d_in[5];
  const float* bk = (const float*)d_in[6];
  const float* wv = (const float*)d_in[7];
  const float* bv = (const float*)d_in[8];
  float* out = (float*)d_out;

  const size_t TS = (size_t)NB*HW*CD;
  unsigned short* qkv = (unsigned short*)d_ws;   // 5*TS bf16
  unsigned short* Og  = qkv + 5*TS;              // 4*TS bf16  [ks][t][b][hw][c]
  float*          Lpw = (float*)(qkv + 9*TS);    // 4*NB*HW f32 [ks][t][b][hw]

  hipLaunchKernelGGL(proj_kernel,    dim3(49,4,5), dim3(256), 0, stream,
                     s,t1,t2,wq,bq,wk,bk,wv,bv,qkv);
  hipLaunchKernelGGL(attn_kernel,    dim3(800),    dim3(256), 0, stream, qkv, Og, Lpw);
  hipLaunchKernelGGL(combine_kernel, dim3(98,8),   dim3(256), 0, stream, s, Og, Lpw, out);
}

// Round 7
// 326.707 us; speedup vs baseline: 1.9851x; 1.9851x over previous
//
#include <hip/hip_runtime.h>

#define HW 3136
#define NB 8
#define CD 128
// C^-0.5 * log2(e), folded into the Q projection so attn uses exp2 directly
#define QSCALE 0.12751750206f

typedef __attribute__((ext_vector_type(8))) short short8;
typedef __attribute__((ext_vector_type(4))) float floatx4;
typedef __attribute__((ext_vector_type(4))) unsigned short ushort4v;

static __device__ __forceinline__ unsigned short f2b(float f){
  union { float f; unsigned u; } v; v.f = f;
  unsigned r = v.u + 0x7FFFu + ((v.u >> 16) & 1u);
  return (unsigned short)(r >> 16);
}
static __device__ __forceinline__ unsigned short f2b_trunc(float f){
  union { float f; unsigned u; } v; v.f = f;
  return (unsigned short)(v.u >> 16);
}
static __device__ __forceinline__ float b2f(unsigned short h){
  union { unsigned u; float f; } v; v.u = ((unsigned)h) << 16;
  return v.f;
}

// ---------------------------------------------------------------------------
// Projections, fused per source: job0 Q<-s; job1 K1,V1<-t1; job2 K2,V2<-t2.
// W in registers (wave owns 32 o-channels), X^T staged in LDS (stride 136 =
// 16B-aligned rows), outputs bounced through LDS for coalesced stores.
// grid (49 hw-tiles, 4 batch-pairs, 3 jobs) = 588 blocks.
// ---------------------------------------------------------------------------
__global__ __launch_bounds__(256) void proj_kernel(
    const float* __restrict__ s, const float* __restrict__ t1, const float* __restrict__ t2,
    const float* __restrict__ wq, const float* __restrict__ bq,
    const float* __restrict__ wk, const float* __restrict__ bk,
    const float* __restrict__ wv, const float* __restrict__ bv,
    unsigned short* __restrict__ qkv)
{
  __shared__ __align__(16) unsigned short XT [64][136];   // 17408 B
  __shared__ __align__(16) unsigned short OTK[64][136];   // 17408 B
  __shared__ __align__(16) unsigned short OTV[128][72];   // 18432 B  (53248 total)
  const int job = blockIdx.z;
  const float* x = (job==0) ? s : (job==1 ? t1 : t2);
  const size_t TS = (size_t)NB*HW*CD;
  unsigned short* dstKbase = (job==0) ? qkv : qkv + (size_t)(2*job - 1)*TS; // Q or K_t
  unsigned short* dstVbase = (job==0) ? 0   : qkv + (size_t)(2*job)*TS;     // V_t
  const float scl = (job==0) ? QSCALE : 1.f;

  const int hw0 = blockIdx.x * 64;
  const int tid = threadIdx.x;
  const int m = tid & 15, quad = (tid >> 4) & 3, wv_ = tid >> 6;

  // W fragments in registers: wave wv_ owns o = (2*wv_+i)*16 + m
  const float* wA = (job==0) ? wq : wk;
  const float* bA = (job==0) ? bq : bk;
  short8 wfA[2][4], wfB[2][4];
  float  bbA[2], bbB[2];
  for (int i=0;i<2;i++){
    int o = (2*wv_ + i)*16 + m;
    bbA[i] = bA[o];
    for (int dk=0;dk<4;dk++){
      const float* wp = wA + (size_t)o*CD + dk*32 + quad*8;
      floatx4 w0 = *(const floatx4*)wp;
      floatx4 w1 = *(const floatx4*)(wp+4);
      short8 f;
      for (int j=0;j<4;j++){ f[j] = (short)f2b(w0[j]); f[4+j] = (short)f2b(w1[j]); }
      wfA[i][dk] = f;
    }
    if (job){
      bbB[i] = bv[o];
      for (int dk=0;dk<4;dk++){
        const float* wp = wv + (size_t)o*CD + dk*32 + quad*8;
        floatx4 w0 = *(const floatx4*)wp;
        floatx4 w1 = *(const floatx4*)(wp+4);
        short8 f;
        for (int j=0;j<4;j++){ f[j] = (short)f2b(w0[j]); f[4+j] = (short)f2b(w1[j]); }
        wfB[i][dk] = f;
      }
    }
  }

  for (int bb2 = 0; bb2 < 2; bb2++){
    const int b = blockIdx.y*2 + bb2;
    __syncthreads();                         // prev batch LDS readers done
    const float* xb = x + (size_t)b*CD*HW + hw0;
    for (int it = 0; it < 8; it++){
      int flat = (tid + it*256)*4;           // c*64 + hh
      int c = flat >> 6, hh = flat & 63;
      floatx4 xv = *(const floatx4*)(xb + (size_t)c*HW + hh);
      for (int j=0;j<4;j++) XT[hh+j][c] = f2b(xv[j]);
    }
    __syncthreads();

    for (int mt=0;mt<4;mt++){
      short8 af[4];
      for (int dk=0;dk<4;dk++)
        af[dk] = *(const short8*)&XT[mt*16 + m][dk*32 + quad*8];
      for (int i=0;i<2;i++){
        floatx4 accK = {bbA[i],bbA[i],bbA[i],bbA[i]};
        for (int dk=0;dk<4;dk++)
          accK = __builtin_amdgcn_mfma_f32_16x16x32_bf16(af[dk], wfA[i][dk], accK, 0,0,0);
        for (int r=0;r<4;r++)
          OTK[mt*16 + quad*4 + r][(2*wv_+i)*16 + m] = f2b(accK[r]*scl);
        if (job){
          floatx4 accV = {bbB[i],bbB[i],bbB[i],bbB[i]};
          for (int dk=0;dk<4;dk++)
            accV = __builtin_amdgcn_mfma_f32_16x16x32_bf16(af[dk], wfB[i][dk], accV, 0,0,0);
          ushort4v pk;
          for (int r=0;r<4;r++) pk[r] = f2b(accV[r]);
          *(ushort4v*)&OTV[(2*wv_+i)*16 + m][mt*16 + quad*4] = pk;
        }
      }
    }
    __syncthreads();

    // coalesced stores from LDS
    unsigned short* dstK = dstKbase + ((size_t)b*HW + hw0)*CD;       // [hw][c]
    for (int i2=0;i2<4;i2++){
      int flat = (tid + i2*256)*8;
      int row = flat >> 7, col = flat & 127;
      *(short8*)&dstK[(size_t)row*CD + col] = *(const short8*)&OTK[row][col];
    }
    if (job){
      unsigned short* dstV = dstVbase + (size_t)b*CD*HW + hw0;       // [c][hw]
      for (int i2=0;i2<4;i2++){
        int flat = (tid + i2*256)*8;
        int o = flat >> 6, col = flat & 63;
        *(short8*)&dstV[(size_t)o*HW + col] = *(const short8*)&OTV[o][col];
      }
    }
  }
}

// ---------------------------------------------------------------------------
// Flash attention: dual 16-row m-tiles per wave, K-tile 64, ksplit=2,
// XCD-grouped grid 800, 16B-ALIGNED LDS strides (136/72/72 shorts).
// Writes unnormalized bf16 O-partials + f32 l-partials.
// ---------------------------------------------------------------------------
#define KSTR 136
#define VSTR 72
#define PSTR 72
#define KL_E (64*KSTR)      // 8704 shorts
#define VL_E (128*VSTR)     // 9216
#define PL_E (4*32*PSTR)    // 9216    -> total 27136 shorts = 54272 B

__global__ __launch_bounds__(256,3) void attn_kernel(
    const unsigned short* __restrict__ qkv,
    unsigned short* __restrict__ Og,
    float* __restrict__ Lp)
{
  __shared__ __align__(16) unsigned short smem[KL_E + VL_E + PL_E];
  unsigned short (*Kl)[KSTR] = (unsigned short(*)[KSTR])smem;
  unsigned short (*Vl)[VSTR] = (unsigned short(*)[VSTR])(smem + KL_E);
  unsigned short (*Pl)[PSTR] = (unsigned short(*)[PSTR])(smem + KL_E + VL_E);

  // lin = (qt*2 + ks)*16 + g : all 50 blocks of one (b,t) share lin mod 16
  const int lin = blockIdx.x;
  const int g   = lin & 15;
  const int qk  = lin >> 4;
  const int qt  = qk >> 1;
  const int ks  = qk & 1;
  const int b   = g >> 1;
  const int t   = g & 1;
  const int kt0 = ks ? 25 : 0;
  const int ktN = ks ? 49 : 25;

  const size_t TS = (size_t)NB*HW*CD;
  const unsigned short* Q = qkv + (size_t)b*HW*CD;
  const unsigned short* K = qkv + TS*(size_t)(1 + 2*t) + (size_t)b*HW*CD;
  const unsigned short* V = qkv + TS*(size_t)(2 + 2*t) + (size_t)b*CD*HW;

  const int tid  = threadIdx.x;
  const int w    = tid >> 6;
  const int lane = tid & 63;
  const int m    = lane & 15;
  const int quad = lane >> 4;
  const int q0w  = qt*128 + w*32;

  short8 qf[2][4];
  for (int mt=0;mt<2;mt++){
    int qrow = q0w + mt*16 + m; if (qrow >= HW) qrow = HW-1;
    const unsigned short* qr = Q + (size_t)qrow*CD + quad*8;
    for (int dk=0;dk<4;dk++) qf[mt][dk] = *(const short8*)(qr + dk*32);
  }
  floatx4 Oc[2][8];
  for (int mt=0;mt<2;mt++) for (int i=0;i<8;i++) Oc[mt][i] = (floatx4)0.f;
  float lr[2][4] = {{0.f,0.f,0.f,0.f},{0.f,0.f,0.f,0.f}};

  const unsigned short* kg = K + (size_t)kt0*64*CD + (size_t)(tid>>4)*CD + (tid&15)*8;
  const unsigned short* vg = V + (size_t)(tid>>3)*HW + kt0*64 + (tid&7)*8;
  unsigned short* klds = &Kl[tid>>4][(tid&15)*8];
  unsigned short* vlds = &Vl[tid>>3][(tid&7)*8];

  short8 kpre[4], vpre[4];
  for (int i=0;i<4;i++) kpre[i] = *(const short8*)(kg + (size_t)i*16*CD);
  for (int i=0;i<4;i++) vpre[i] = *(const short8*)(vg + (size_t)i*32*HW);

  for (int kt = kt0; kt < ktN; kt++){
    __syncthreads();
    for (int i=0;i<4;i++) *(short8*)(klds + i*16*KSTR) = kpre[i];
    for (int i=0;i<4;i++) *(short8*)(vlds + i*32*VSTR) = vpre[i];
    __syncthreads();
    if (kt < ktN - 1){
      kg += 64*CD; vg += 64;
      for (int i=0;i<4;i++) kpre[i] = *(const short8*)(kg + (size_t)i*16*CD);
      for (int i=0;i<4;i++) vpre[i] = *(const short8*)(vg + (size_t)i*32*HW);
    }

    // scores per nt-tile: each kf read feeds both m-tiles
    for (int nt=0;nt<4;nt++){
      floatx4 s0 = (floatx4)0.f, s1 = (floatx4)0.f;
      for (int dk=0;dk<4;dk++){
        short8 kf = *(const short8*)&Kl[nt*16 + m][dk*32 + quad*8];
        s0 = __builtin_amdgcn_mfma_f32_16x16x32_bf16(qf[0][dk], kf, s0, 0,0,0);
        s1 = __builtin_amdgcn_mfma_f32_16x16x32_bf16(qf[1][dk], kf, s1, 0,0,0);
      }
      for (int r=0;r<4;r++){
        float p0 = __builtin_amdgcn_exp2f(s0[r]);
        float p1 = __builtin_amdgcn_exp2f(s1[r]);
        lr[0][r] += p0;
        lr[1][r] += p1;
        Pl[w*32      + quad*4 + r][nt*16 + m] = f2b_trunc(p0);
        Pl[w*32 + 16 + quad*4 + r][nt*16 + m] = f2b_trunc(p1);
      }
    }
    __asm__ volatile("s_waitcnt lgkmcnt(0)" ::: "memory");  // same-wave P rows
    short8 pf[2][2];
    for (int mt=0;mt<2;mt++)
      for (int kk=0;kk<2;kk++)
        pf[mt][kk] = *(const short8*)&Pl[w*32 + mt*16 + m][kk*32 + quad*8];
    for (int ct=0;ct<8;ct++){
      short8 vf0 = *(const short8*)&Vl[ct*16 + m][quad*8];
      short8 vf1 = *(const short8*)&Vl[ct*16 + m][32 + quad*8];
      Oc[0][ct] = __builtin_amdgcn_mfma_f32_16x16x32_bf16(pf[0][0], vf0, Oc[0][ct], 0,0,0);
      Oc[0][ct] = __builtin_amdgcn_mfma_f32_16x16x32_bf16(pf[0][1], vf1, Oc[0][ct], 0,0,0);
      Oc[1][ct] = __builtin_amdgcn_mfma_f32_16x16x32_bf16(pf[1][0], vf0, Oc[1][ct], 0,0,0);
      Oc[1][ct] = __builtin_amdgcn_mfma_f32_16x16x32_bf16(pf[1][1], vf1, Oc[1][ct], 0,0,0);
    }
  }

  // l partial: reduce across the 16 column-lanes of each quad (no normalize)
  for (int mt=0;mt<2;mt++)
    for (int r=0;r<4;r++)
      for (int off=1; off<16; off<<=1)
        lr[mt][r] += __shfl_xor(lr[mt][r], off, 64);

  __syncthreads();                          // done with K/V/P LDS; reuse as staging
  unsigned short* stg = smem + w*(32*KSTR); // 32x136 bf16 per wave
  for (int mt=0;mt<2;mt++)
    for (int ct=0;ct<8;ct++)
      for (int r=0;r<4;r++)
        stg[(mt*16 + quad*4 + r)*KSTR + ct*16 + m] = f2b(Oc[mt][ct][r]);
  __asm__ volatile("s_waitcnt lgkmcnt(0)" ::: "memory");    // per-wave region
  if (q0w < HW){
    const size_t strm = (size_t)(ks*2 + t)*NB + b;
    unsigned short* ob = Og + strm*HW*CD + (size_t)q0w*CD;
    for (int i=0;i<8;i++){
      int row = i*4 + quad;
      short8 v8 = *(const short8*)&stg[row*KSTR + m*8];
      *(short8*)&ob[(size_t)row*CD + m*8] = v8;
    }
    if (m == 0){
      float* lb = Lp + strm*HW + q0w;
      for (int mt=0;mt<2;mt++)
        for (int r=0;r<4;r++)
          lb[mt*16 + quad*4 + r] = lr[mt][r];
    }
  }
}

// ---------------------------------------------------------------------------
// out[b,c,hw] = s + 0.5 * sum_t (O_t0+O_t1)/(l_t0+l_t1)   (partial combine)
// ---------------------------------------------------------------------------
__global__ __launch_bounds__(256) void combine_kernel(
    const float* __restrict__ s, const unsigned short* __restrict__ Og,
    const float* __restrict__ Lp, float* __restrict__ out)
{
  __shared__ float T[32][129];
  const int b   = blockIdx.y;
  const int hw0 = blockIdx.x * 32;
  const int tid = threadIdx.x;
  const size_t OS = (size_t)NB*HW*CD;
  const size_t LS = (size_t)NB*HW;
  const unsigned short* Ob = Og + ((size_t)b*HW + hw0)*CD;
  const float* Lb = Lp + (size_t)b*HW + hw0;

  for (int i=0;i<2;i++){
    int flat = (tid + i*256)*8;
    int row = flat >> 7, col = flat & 127;
    size_t off = (size_t)row*CD + col;
    short8 o00 = *(const short8*)(Ob + off);
    short8 o01 = *(const short8*)(Ob + OS   + off);
    short8 o10 = *(const short8*)(Ob + 2*OS + off);
    short8 o11 = *(const short8*)(Ob + 3*OS + off);
    float inv0 = 1.f / (Lb[row] + Lb[2*LS + row]);
    float inv1 = 1.f / (Lb[LS + row] + Lb[3*LS + row]);
    for (int j=0;j<8;j++)
      T[row][col+j] = 0.5f*((b2f((unsigned short)o00[j]) + b2f((unsigned short)o10[j]))*inv0
                          + (b2f((unsigned short)o01[j]) + b2f((unsigned short)o11[j]))*inv1);
  }
  __syncthreads();
  const int c  = tid >> 1;
  const int h0 = (tid & 1)*16;
  const float* sr = s   + ((size_t)b*CD + c)*HW + hw0 + h0;
  float*     orow = out + ((size_t)b*CD + c)*HW + hw0 + h0;
  for (int j0=0;j0<16;j0+=4){
    floatx4 sv = *(const floatx4*)(sr + j0);
    floatx4 ov;
    for (int jj=0;jj<4;jj++) ov[jj] = sv[jj] + T[h0+j0+jj][c];
    *(floatx4*)(orow + j0) = ov;
  }
}

extern "C" void kernel_launch(void* const* d_in, const int* in_sizes, int n_in,
                              void* d_out, int out_size, void* d_ws, size_t ws_size,
                              hipStream_t stream)
{
  const float* s  = (const float*)d_in[0];
  const float* t1 = (const float*)d_in[1];
  const float* t2 = (const float*)d_in[2];
  const float* wq = (const float*)d_in[3];
  const float* bq = (const float*)d_in[4];
  const float* wk = (const float*)d_in[5];
  const float* bk = (const float*)d_in[6];
  const float* wv = (const float*)d_in[7];
  const float* bv = (const float*)d_in[8];
  float* out = (float*)d_out;

  const size_t TS = (size_t)NB*HW*CD;
  unsigned short* qkv = (unsigned short*)d_ws;   // 5*TS bf16
  unsigned short* Og  = qkv + 5*TS;              // 4*TS bf16  [ks][t][b][hw][c]
  float*          Lpw = (float*)(qkv + 9*TS);    // 4*NB*HW f32 [ks][t][b][hw]

  hipLaunchKernelGGL(proj_kernel,    dim3(49,4,3), dim3(256), 0, stream,
                     s,t1,t2,wq,bq,wk,bk,wv,bv,qkv);
  hipLaunchKernelGGL(attn_kernel,    dim3(800),    dim3(256), 0, stream, qkv, Og, Lpw);
  hipLaunchKernelGGL(combine_kernel, dim3(98,8),   dim3(256), 0, stream, s, Og, Lpw, out);
}